// Round 6
// baseline (329.155 us; speedup 1.0000x reference)
//
#include <hip/hip_runtime.h>
#include <hip/hip_bf16.h>
#include <cstdint>
#include <cstddef>

// Problem: B=4, T=4096, D=1024, H=16, HD=64.
// qkv = x @ Wqkv  (16384x1024 @ 1024x3072)
// per-token head-attention: scores[i,j] = q_i . k_j / 8 over heads i,j (16x16), softmax_j, out = P @ v
// final = out @ Wout (16384x1024 @ 1024x1024)
//
// qkv/ao stored permuted per token (absorbed into weight transposes) so attn
// is fully coalesced.
// GEMM: rounds 0-5 established (measured, 121 us invariant across 5 schedules)
// that the kernel is LDS-BANDWIDTH-bound: LDS bytes per tile / 112 B/cyc/CU
// matched the measured pace within 5% while MfmaUtil sat at 37%. Fix = cut
// LDS bytes per FLOP: 256x256 tile, 8 waves 2Mx4N (wave-tile 128x64):
// (256*4+256*2)*64 = 96 KB reads + 32 KB writes per 4.2 MFLOP = 30.5 B/KFLOP
// (vs 42.6 in round 5) -> LDS time ~= MFMA time per tile (1143 vs 1034 cyc).
// Keep round-5's loose schedule: 3-slot BK=32 ring (96 KiB, 1 block/CU),
// depth-2 prefetch, counted vmcnt(4) (never 0 mid-loop), ONE barrier per
// K-tile, no lgkm walls (compiler emits counted lgkmcnt for ds_read->MFMA).

typedef __bf16 bf16x8 __attribute__((ext_vector_type(8)));
typedef __bf16 bf16x4 __attribute__((ext_vector_type(4)));
typedef float  f32x4  __attribute__((ext_vector_type(4)));

#define AS1 __attribute__((address_space(1)))
#define AS3 __attribute__((address_space(3)))

__device__ __forceinline__ void async_copy16(const void* g, void* l) {
    __builtin_amdgcn_global_load_lds((const AS1 void*)g, (AS3 void*)l, 16, 0, 0);
}

// position p in the permuted qkv token-row holds original column pi(p).
// q/k (g<2): col=g*1024+h*64+d -> p = g*1024 + (d&32)*16 + ((d>>3)&3)*128 + h*8 + (d&7)
// v (g==2): col=2048+j*64+d -> p = 2048 + d*16 + j   (V transposed: B-frag direct load)
__device__ __forceinline__ int invp_qkv(int col) {
    int g = col >> 10;
    if (g == 2) { int q = col & 1023; return 2048 + ((q & 63) << 4) + (q >> 6); }
    int h = (col >> 6) & 15, d = col & 63;
    return (g << 10) + ((d & 32) << 4) + (((d >> 3) & 3) << 7) + (h << 3) + (d & 7);
}

// ao position map: original k = i*64+d -> p = (i>>2)*256 + (d&15)*16 + (d>>4)*4 + (i&3)
__device__ __forceinline__ int invp_ao(int k) {
    return (((k >> 8) & 3) << 8) + ((k & 15) << 4) + (((k >> 4) & 3) << 2) + ((k >> 6) & 3);
}

// ---------------- convert fp32 -> bf16 (vectorized) ----------------
__global__ __launch_bounds__(256) void cvt_bf16_kernel(const float4* __restrict__ in,
                                                       bf16x4* __restrict__ out, int n4) {
    int i = blockIdx.x * 256 + threadIdx.x;
    if (i >= n4) return;
    float4 v = in[i];
    bf16x4 o = { (__bf16)v.x, (__bf16)v.y, (__bf16)v.z, (__bf16)v.w };
    out[i] = o;
}

// ---------------- transpose + convert Wqkv: out row order permuted ----------------
__global__ __launch_bounds__(256) void transpose_qkv_kernel(const float* __restrict__ in,
                                                            __bf16* __restrict__ out) {
    __shared__ float tile[32][33];
    const int C = 3072;
    int c0 = blockIdx.x * 32, r0 = blockIdx.y * 32;
    int tx = threadIdx.x, ty = threadIdx.y; // 32 x 8
    #pragma unroll
    for (int i = 0; i < 32; i += 8)
        tile[ty + i][tx] = in[(size_t)(r0 + ty + i) * C + c0 + tx];
    __syncthreads();
    #pragma unroll
    for (int i = 0; i < 32; i += 8) {
        int prow = invp_qkv(c0 + ty + i);
        out[(size_t)prow * 1024 + r0 + tx] = (__bf16)tile[tx][ty + i];
    }
}

// ---------------- transpose + convert Wout: k (inner) order permuted ----------------
__global__ __launch_bounds__(256) void transpose_wout_kernel(const float* __restrict__ in,
                                                             __bf16* __restrict__ out) {
    __shared__ float tile[32][33];
    const int C = 1024;
    int c0 = blockIdx.x * 32, r0 = blockIdx.y * 32;
    int tx = threadIdx.x, ty = threadIdx.y; // 32 x 8
    #pragma unroll
    for (int i = 0; i < 32; i += 8)
        tile[ty + i][tx] = in[(size_t)(r0 + ty + i) * C + c0 + tx];
    __syncthreads();
    int pk = invp_ao(r0 + tx);
    #pragma unroll
    for (int i = 0; i < 32; i += 8)
        out[(size_t)(c0 + ty + i) * 1024 + pk] = (__bf16)tile[tx][ty + i];
}

// ---------------- bf16 GEMM, C = A @ Bt^T, 256x256 tile, BK=32, 3-slot ring ----
// A: M x K bf16 row-major, Bt: N x K bf16 row-major. 512 threads = 8 waves
// (2Mx4N), each wave owns a 128x64 output (acc[8][4] of 16x16 frags = 128 VGPR).
// LDS: 3-slot ring; slot = A 256x32 (16 KB) + B 256x32 (16 KB). 96 KiB total
// -> 1 block/CU. Conflict-free involution phys = logical ^ ((row>>1)&3)
// (64 B rows repeat banks every 2 rows); staged via pre-swizzled global source
// so global_load_lds dest stays linear.
// Per K-tile t: STAGE(t+2) (4 glds) | read 12 frags from slot t%3 | 32 MFMA
// (compiler interleaves via counted lgkmcnt; waves slip freely inside the
// barrier window) | sched_barrier | vmcnt(4) | s_barrier.
// WAR: STAGE(t+2) overwrites slot (t-1)%3; all waves' tile-(t-1) ds_reads
// completed before their MFMAs (compiler lgkm), which precede barrier(t-1).
// RAW: end-of-t wall leaves only S(t+2)'s 4 loads in flight -> t+1 landed.
// Tail: vmcnt(0) at t >= NT-2. Assumes K % 32 == 0, K >= 96 (here K=1024).
template<int OUT_BF16>
__global__ __launch_bounds__(512, 2) void gemm_bt(const __bf16* __restrict__ A,
                                                  const __bf16* __restrict__ Bt,
                                                  void* __restrict__ Cv,
                                                  int N, int K) {
    __shared__ __attribute__((aligned(16))) __bf16 As[3 * 256 * 32]; // 48 KB ring
    __shared__ __attribute__((aligned(16))) __bf16 Bs[3 * 256 * 32]; // 48 KB ring

    // XCD-band swizzle (grid = 8 * nbx * 8): each XCD owns 8 consecutive
    // A-bands (by), walks bx outer / by inner -> A-bands stay L2-resident.
    const int lin = blockIdx.x;
    const int xcd = lin & 7;
    const int rr  = lin >> 3;
    const int by  = xcd * 8 + (rr & 7);
    const int bx  = rr >> 3;

    const int tid  = threadIdx.x;
    const int wave = tid >> 6;
    const int lane = tid & 63;
    const int quad = lane >> 4;
    const int q16  = lane & 15;
    const int wr   = wave >> 2, wc = wave & 3;  // 2 x 4 wave grid
    const int row0 = by * 256;
    const int col0 = bx * 256;

    const __bf16* Ag = A  + (size_t)row0 * K;
    const __bf16* Bg = Bt + (size_t)col0 * K;

    // staging: thread covers row tid>>2 (and +128 for the second half), phys
    // kslot tid&3; source k pre-swizzled so logical slot at phys p is
    // p ^ ((row>>1)&3). (row>>1)&3 is invariant under row += 128.
    const int srow = tid >> 2;                              // 0..127
    const int sk   = ((tid & 3) ^ ((srow >> 1) & 3)) << 3;  // element k-offset
    const __bf16* aSrc = Ag + (size_t)srow * K + sk;
    const __bf16* bSrc = Bg + (size_t)srow * K + sk;
    char* aDst = (char*)As + tid * 16;
    char* bDst = (char*)Bs + tid * 16;

    // frag read: phys = quad ^ ((row>>1)&3); (row>>1)&3 == (q16>>1)&3 for
    // every frag row (row bases are multiples of 16).
    const int pxo  = (quad ^ ((q16 >> 1) & 3)) << 4;
    const int aoff = wr * 8192 + q16 * 64 + pxo;   // + mi*1024 (mi 0..7)
    const int boff = wc * 4096 + q16 * 64 + pxo;   // + ni*1024 (ni 0..3)

    f32x4 acc[8][4] = {};

    const int NT = K >> 5;

#define STAGE(t) do { \
        const size_t so_ = (size_t)(t) * 32; \
        const int   sl_  = (t) % 3; \
        async_copy16(aSrc + so_,                   aDst + sl_ * 16384); \
        async_copy16(aSrc + (size_t)128 * K + so_, aDst + sl_ * 16384 + 8192); \
        async_copy16(bSrc + so_,                   bDst + sl_ * 16384); \
        async_copy16(bSrc + (size_t)128 * K + so_, bDst + sl_ * 16384 + 8192); \
    } while (0)

    // prologue: stage tiles 0,1 (8 glds/thread); wait tile 0 (S(1)'s 4 remain)
    STAGE(0);
    STAGE(1);
    asm volatile("s_waitcnt vmcnt(4)" ::: "memory");
    __builtin_amdgcn_s_barrier();
    __builtin_amdgcn_sched_barrier(0);

    #pragma unroll 1
    for (int t = 0; t < NT; ++t) {
        if (t + 2 < NT) STAGE(t + 2);
        const int slot = t % 3;
        const char* Ab = (const char*)As + slot * 16384;
        const char* Bb = (const char*)Bs + slot * 16384;
        bf16x8 af[8], bf[4];
        #pragma unroll
        for (int mi = 0; mi < 8; ++mi)
            af[mi] = *(const bf16x8*)(Ab + aoff + mi * 1024);
        #pragma unroll
        for (int ni = 0; ni < 4; ++ni)
            bf[ni] = *(const bf16x8*)(Bb + boff + ni * 1024);
        __builtin_amdgcn_s_setprio(1);
        #pragma unroll
        for (int mi = 0; mi < 8; ++mi)
            #pragma unroll
            for (int ni = 0; ni < 4; ++ni)
                acc[mi][ni] = __builtin_amdgcn_mfma_f32_16x16x32_bf16(af[mi], bf[ni], acc[mi][ni], 0, 0, 0);
        __builtin_amdgcn_s_setprio(0);
        __builtin_amdgcn_sched_barrier(0);
        if (t < NT - 2) asm volatile("s_waitcnt vmcnt(4)" ::: "memory");
        else            asm volatile("s_waitcnt vmcnt(0)" ::: "memory");
        __builtin_amdgcn_s_barrier();
        __builtin_amdgcn_sched_barrier(0);
    }
#undef STAGE

    // epilogue: D row = quad*4 + r, col = q16 (per 16x16 tile)
    #pragma unroll
    for (int mi = 0; mi < 8; ++mi) {
        #pragma unroll
        for (int ni = 0; ni < 4; ++ni) {
            const int col = col0 + wc * 64 + ni * 16 + q16;
            #pragma unroll
            for (int r = 0; r < 4; ++r) {
                const int row = row0 + wr * 128 + mi * 16 + quad * 4 + r;
                if (OUT_BF16)
                    ((__bf16*)Cv)[(size_t)row * N + col] = (__bf16)acc[mi][ni][r];
                else
                    ((float*)Cv)[(size_t)row * N + col] = acc[mi][ni][r];
            }
        }
    }
}

// ---------------- per-token head attention, MFMA, one wave per token ----------------
// qkv token-row is in permuted layout (see invp_qkv): all loads coalesced,
// V pre-transposed -> direct B-frag loads. No LDS, no barriers.
__global__ __launch_bounds__(256) void attn_mfma_kernel(const __bf16* __restrict__ qkv,
                                                        __bf16* __restrict__ ao) {
    const int tok  = blockIdx.x * 4 + (threadIdx.x >> 6);
    const int lane = threadIdx.x & 63;
    const int quad = lane >> 4;
    const int q16  = lane & 15;

    const __bf16* base = qkv + (size_t)tok * 3072;

    // coalesced A-frag loads (layout puts lane's fragment at lane*8)
    const bf16x8 qf0 = *(const bf16x8*)(base + lane * 8);
    const bf16x8 qf1 = *(const bf16x8*)(base + 512 + lane * 8);
    const bf16x8 kf0 = *(const bf16x8*)(base + 1024 + lane * 8);
    const bf16x8 kf1 = *(const bf16x8*)(base + 1536 + lane * 8);

    // S^T[j][i] = sum_d k[j][d] q[i][d]
    f32x4 st = {0.f, 0.f, 0.f, 0.f};
    st = __builtin_amdgcn_mfma_f32_16x16x32_bf16(kf0, qf0, st, 0, 0, 0);
    st = __builtin_amdgcn_mfma_f32_16x16x32_bf16(kf1, qf1, st, 0, 0, 0);

    // softmax over j (= 4 regs x 4 quads) for fixed i = q16
    float s0 = st[0] * 0.125f, s1 = st[1] * 0.125f, s2 = st[2] * 0.125f, s3 = st[3] * 0.125f;
    float m = fmaxf(fmaxf(s0, s1), fmaxf(s2, s3));
    m = fmaxf(m, __shfl_xor(m, 16));
    m = fmaxf(m, __shfl_xor(m, 32));
    float e0 = __expf(s0 - m), e1 = __expf(s1 - m), e2 = __expf(s2 - m), e3 = __expf(s3 - m);
    float sum = e0 + e1 + e2 + e3;
    sum += __shfl_xor(sum, 16);
    sum += __shfl_xor(sum, 32);
    const float inv = 1.f / sum;

    // pack P^T lane values (j = quad*4 + r, i = q16) into 2 dwords of bf16
    union { __bf16 h[2]; int i; } u01, u23;
    u01.h[0] = (__bf16)(e0 * inv); u01.h[1] = (__bf16)(e1 * inv);
    u23.h[0] = (__bf16)(e2 * inv); u23.h[1] = (__bf16)(e3 * inv);

    // A-frag of P for 16x16x32 (K padded to 32): lane needs P[q16][quad*8+idx]
    const int src0 = quad * 32 + q16;
    const int src1 = src0 + 16;
    union { int i[4]; bf16x8 v; } af;
    af.i[0] = __shfl(u01.i, src0);
    af.i[1] = __shfl(u23.i, src0);
    af.i[2] = __shfl(u01.i, src1);
    af.i[3] = __shfl(u23.i, src1);
    if (quad >= 2) { af.i[0] = 0; af.i[1] = 0; af.i[2] = 0; af.i[3] = 0; }

    // PV: V region is pre-transposed [d][j]; B-frag chunk c is a direct load.
    const __bf16* vb = base + 2048;
    f32x4 accs[4];
    #pragma unroll
    for (int c = 0; c < 4; ++c) {
        bf16x8 bfv = {};
        if (quad < 2)
            bfv = *(const bf16x8*)(vb + (c * 16 + q16) * 16 + quad * 8);
        f32x4 z = {0.f, 0.f, 0.f, 0.f};
        accs[c] = __builtin_amdgcn_mfma_f32_16x16x32_bf16(af.v, bfv, z, 0, 0, 0);
    }

    // store: lane's 16 values contiguously at p = lane*16 (invp_ao layout)
    union { __bf16 h[16]; bf16x8 v[2]; } o;
    #pragma unroll
    for (int c = 0; c < 4; ++c)
        #pragma unroll
        for (int r = 0; r < 4; ++r)
            o.h[c * 4 + r] = (__bf16)accs[c][r];
    __bf16* outp = ao + (size_t)tok * 1024 + lane * 16;
    *(bf16x8*)outp = o.v[0];
    *(bf16x8*)(outp + 8) = o.v[1];
}

// ---------------- launch ----------------
extern "C" void kernel_launch(void* const* d_in, const int* in_sizes, int n_in,
                              void* d_out, int out_size, void* d_ws, size_t ws_size,
                              hipStream_t stream) {
    const float* x    = (const float*)d_in[0]; // 16384 x 1024
    const float* Wqkv = (const float*)d_in[1]; // 1024 x 3072
    const float* Wout = (const float*)d_in[2]; // 1024 x 1024
    float* out = (float*)d_out;                // 16384 x 1024

    char* ws = (char*)d_ws;
    __bf16* xb    = (__bf16*)(ws);                                   // 32 MiB
    __bf16* wqkvT = (__bf16*)(ws + 33554432);                        // 6 MiB  (3072 x 1024, row-permuted)
    __bf16* woutT = (__bf16*)(ws + 33554432 + 6291456);              // 2 MiB  (1024 x 1024, k-permuted)
    __bf16* qkv   = (__bf16*)(ws + 33554432 + 6291456 + 2097152);    // 96 MiB (16384 x 3072, permuted)
    __bf16* ao    = (__bf16*)(ws + 33554432 + 6291456 + 2097152 + 100663296); // 32 MiB (permuted)

    // convert x (16M elems, 4/thread)
    cvt_bf16_kernel<<<16384, 256, 0, stream>>>((const float4*)x, (bf16x4*)xb, 4194304);
    // transpose+convert weights (with absorbed layout permutations)
    transpose_qkv_kernel<<<dim3(96, 32), dim3(32, 8), 0, stream>>>(Wqkv, wqkvT);
    transpose_wout_kernel<<<dim3(32, 32), dim3(32, 8), 0, stream>>>(Wout, woutT);
    // GEMM1: qkv = xb @ wqkvT^T (16384 x 3072), 256x256 tiles: 64 x 12 = 768 blocks
    gemm_bt<1><<<768, 512, 0, stream>>>(xb, wqkvT, (void*)qkv, 3072, 1024);
    // per-token attention (one wave per token, 4 waves/block, no LDS/barrier)
    attn_mfma_kernel<<<4096, 256, 0, stream>>>(qkv, ao);
    // GEMM2: out = ao @ woutT^T (fp32 out), 256x256 tiles: 64 x 4 = 256 blocks
    gemm_bt<0><<<256, 512, 0, stream>>>(ao, woutT, (void*)out, 1024, 1024);
}

// Round 7
// 296.275 us; speedup vs baseline: 1.1110x; 1.1110x over previous
//
#include <hip/hip_runtime.h>
#include <hip/hip_bf16.h>
#include <cstdint>
#include <cstddef>

// Problem: B=4, T=4096, D=1024, H=16, HD=64.
// qkv = x @ Wqkv; per-token 16x16 head-attention; out = ao @ Wout.
//
// GEMM this round: m201-style FINE-PHASE schedule (the verified 1563-TF
// structure). 256x256 tile, BK=64, 8 waves 2Mx4N (wave-tile 128x64).
// 4 sub-phases per K-tile, each = {ds_read quadrant frags | stage 1-2 units
// of tile t+1 | barrier | lgkm(0) | setprio(1) 16 MFMA setprio(0) | [vmcnt]
// barrier}. Quadrant read order fully consumes each A/B slice by a known
// phase, so tile t+1 units stage IN-PLACE into the single 64 KiB buffer:
//   ph1: read A-u1(mi0-3) + B-u1(ni0-1) [12 rds] | -            | MFMA Q00
//   ph2: read B-u2(ni2-3)               [ 4 rds] | stage A-u1'  | MFMA Q01
//   ph3: read A-u2(mi4-7)               [ 8 rds] | stage B-u1'+B-u2' | Q10
//   ph4: -                                       | stage A-u2'  | MFMA Q11
// WAR: A-u1 rows last read in ph1 -> ph1-end barrier precedes ph2's stage;
// B last read ph2 -> ph3 stage safe; A-u2 last read ph3 -> ph4 stage safe.
// RAW gates (loads/thread; issue order Au1',Bu1',Bu2',Au2', 2 each):
//   end-ph1: vmcnt(2) -> Bu2(t) landed (ph2 reads it)
//   end-ph2: vmcnt(2) -> Au2(t) landed (ph3 reads it; queue has Au2,Au1')
//   end-ph4: vmcnt(4) -> Au1',Bu1' landed (ph1(t+1) reads them)
// Never drained to 0 mid-loop; tail-safe (gates pass through when queue
// short). Swizzle: round-0 involution phys_slot = slot ^ (row&7) on 128-B
// rows (measured 0 conflicts), staged via pre-swizzled global source so
// global_load_lds dest stays linear.

typedef __bf16 bf16x8 __attribute__((ext_vector_type(8)));
typedef __bf16 bf16x4 __attribute__((ext_vector_type(4)));
typedef float  f32x4  __attribute__((ext_vector_type(4)));

#define AS1 __attribute__((address_space(1)))
#define AS3 __attribute__((address_space(3)))

__device__ __forceinline__ void async_copy16(const void* g, void* l) {
    __builtin_amdgcn_global_load_lds((const AS1 void*)g, (AS3 void*)l, 16, 0, 0);
}

// position p in the permuted qkv token-row holds original column pi(p).
__device__ __forceinline__ int invp_qkv(int col) {
    int g = col >> 10;
    if (g == 2) { int q = col & 1023; return 2048 + ((q & 63) << 4) + (q >> 6); }
    int h = (col >> 6) & 15, d = col & 63;
    return (g << 10) + ((d & 32) << 4) + (((d >> 3) & 3) << 7) + (h << 3) + (d & 7);
}

// ao position map: original k = i*64+d -> p = (i>>2)*256 + (d&15)*16 + (d>>4)*4 + (i&3)
__device__ __forceinline__ int invp_ao(int k) {
    return (((k >> 8) & 3) << 8) + ((k & 15) << 4) + (((k >> 4) & 3) << 2) + ((k >> 6) & 3);
}

// ---------------- convert fp32 -> bf16 (vectorized) ----------------
__global__ __launch_bounds__(256) void cvt_bf16_kernel(const float4* __restrict__ in,
                                                       bf16x4* __restrict__ out, int n4) {
    int i = blockIdx.x * 256 + threadIdx.x;
    if (i >= n4) return;
    float4 v = in[i];
    bf16x4 o = { (__bf16)v.x, (__bf16)v.y, (__bf16)v.z, (__bf16)v.w };
    out[i] = o;
}

// ---------------- transpose + convert Wqkv: out row order permuted ----------------
__global__ __launch_bounds__(256) void transpose_qkv_kernel(const float* __restrict__ in,
                                                            __bf16* __restrict__ out) {
    __shared__ float tile[32][33];
    const int C = 3072;
    int c0 = blockIdx.x * 32, r0 = blockIdx.y * 32;
    int tx = threadIdx.x, ty = threadIdx.y; // 32 x 8
    #pragma unroll
    for (int i = 0; i < 32; i += 8)
        tile[ty + i][tx] = in[(size_t)(r0 + ty + i) * C + c0 + tx];
    __syncthreads();
    #pragma unroll
    for (int i = 0; i < 32; i += 8) {
        int prow = invp_qkv(c0 + ty + i);
        out[(size_t)prow * 1024 + r0 + tx] = (__bf16)tile[tx][ty + i];
    }
}

// ---------------- transpose + convert Wout: k (inner) order permuted ----------------
__global__ __launch_bounds__(256) void transpose_wout_kernel(const float* __restrict__ in,
                                                             __bf16* __restrict__ out) {
    __shared__ float tile[32][33];
    const int C = 1024;
    int c0 = blockIdx.x * 32, r0 = blockIdx.y * 32;
    int tx = threadIdx.x, ty = threadIdx.y; // 32 x 8
    #pragma unroll
    for (int i = 0; i < 32; i += 8)
        tile[ty + i][tx] = in[(size_t)(r0 + ty + i) * C + c0 + tx];
    __syncthreads();
    int pk = invp_ao(r0 + tx);
    #pragma unroll
    for (int i = 0; i < 32; i += 8)
        out[(size_t)(c0 + ty + i) * 1024 + pk] = (__bf16)tile[tx][ty + i];
}

// ---------------- bf16 GEMM, C = A @ Bt^T, 256x256 tile, BK=64, fine phases ----
// A: M x K bf16 row-major, Bt: N x K bf16 row-major. 512 threads = 8 waves
// (2Mx4N), wave-tile 128x64, acc[8][4]. LDS: SINGLE buffer, A 256x64 (32 KB)
// + B 256x64 (32 KB) = 64 KiB. Row = 128 B = 8 x 16B slots, phys = slot ^
// (row&7). Units: A-u1 = rows {0-63,128-191} (mi0-3 of both wr), A-u2 = the
// rest; B-u1 = 32-col stripes ni0-1 of each wave (rows {0-31,64-95,...}),
// B-u2 = the rest. Unit = 16 KB = 2 glds/thread.
// Assumes K % 64 == 0, K >= 128 (here K = 1024, NT = 16).
template<int OUT_BF16>
__global__ __launch_bounds__(512, 2) void gemm_bt(const __bf16* __restrict__ A,
                                                  const __bf16* __restrict__ Bt,
                                                  void* __restrict__ Cv,
                                                  int N, int K) {
    __shared__ __attribute__((aligned(16))) __bf16 As[256 * 64]; // 32 KB
    __shared__ __attribute__((aligned(16))) __bf16 Bs[256 * 64]; // 32 KB

    // XCD-band swizzle (nby = 64, grid = 8*8*nbx): each XCD owns 8 consecutive
    // A-bands (by), walks bx outer / by inner.
    const int lin = blockIdx.x;
    const int xcd = lin & 7;
    const int rr  = lin >> 3;
    const int by  = xcd * 8 + (rr & 7);
    const int bx  = rr >> 3;

    const int tid  = threadIdx.x;
    const int wave = tid >> 6;
    const int lane = tid & 63;
    const int quad = lane >> 4;
    const int q16  = lane & 15;
    const int wr   = wave >> 2, wc = wave & 3;  // 2 x 4 wave grid
    const int row0 = by * 256;
    const int col0 = bx * 256;

    const __bf16* Ag = A  + (size_t)row0 * K;
    const __bf16* Bg = Bt + (size_t)col0 * K;

    // ---- staging addressing (per thread) ----
    // A: rowIdx = tid>>3 (0..63), slot = tid&7; per-load row = base + rowIdx
    //    (bases 0/128 for u1, 64/192 for u2; all %8==0 so row&7 = rowIdx&7).
    // B: brg = rgrp + (rgrp&32) maps rgrp 0..63 -> {0..31, 64..95}; per-load
    //    row = S0 + brg with S0 in {0,128} (u1) / {32,160} (u2).
    // Source k pre-swizzled: sk = ((slot ^ (rowIdx&7)) << 3) elements.
    const int rowIdx = tid >> 3;
    const int slotq  = tid & 7;
    const int skel   = ((slotq ^ (rowIdx & 7)) << 3);
    const int brg    = rowIdx + (rowIdx & 32);
    const __bf16* aSrc = Ag + (size_t)rowIdx * K + skel;
    const __bf16* bSrc = Bg + (size_t)brg * K + skel;
    char* aDst = (char*)As + rowIdx * 128 + slotq * 16;
    char* bDst = (char*)Bs + brg * 128 + slotq * 16;

    // ---- fragment read addressing ----
    // A-frag(mi,kk): row = wr*128 + mi*16 + q16; B-frag(ni,kk): row = wc*64 +
    // ni*16 + q16; phys slot = (kk*4+quad) ^ (q16&7).
    const int px0   = ((quad ^ (q16 & 7)) << 4);
    const int px1   = px0 ^ 64;
    const int aBase = (wr * 128 + q16) * 128;
    const int bBase = (wc * 64 + q16) * 128;
    const char* AsB = (const char*)As;
    const char* BsB = (const char*)Bs;

    f32x4 acc[8][4] = {};
    bf16x8 af[4][2], bf[4][2];

    const int NT = K >> 6;

#define STAGE_A(t, u) do { \
        const size_t ko_ = (size_t)(t) * 64; \
        const int b0_ = (u) ? 64 : 0, b1_ = (u) ? 192 : 128; \
        async_copy16(aSrc + (size_t)b0_ * K + ko_, aDst + b0_ * 128); \
        async_copy16(aSrc + (size_t)b1_ * K + ko_, aDst + b1_ * 128); \
    } while (0)
#define STAGE_B(t, u) do { \
        const size_t ko_ = (size_t)(t) * 64; \
        const int s0_ = (u) ? 32 : 0, s1_ = (u) ? 160 : 128; \
        async_copy16(bSrc + (size_t)s0_ * K + ko_, bDst + s0_ * 128); \
        async_copy16(bSrc + (size_t)s1_ * K + ko_, bDst + s1_ * 128); \
    } while (0)
#define SB0() __builtin_amdgcn_sched_barrier(0)
#define MFMA_Q(a, b) do { \
        _Pragma("unroll") \
        for (int kk = 0; kk < 2; ++kk) \
            _Pragma("unroll") \
            for (int mi = 0; mi < 4; ++mi) \
                _Pragma("unroll") \
                for (int ni = (b)*2; ni < (b)*2 + 2; ++ni) \
                    acc[(a)*4 + mi][ni] = __builtin_amdgcn_mfma_f32_16x16x32_bf16( \
                        af[mi][kk], bf[ni][kk], acc[(a)*4 + mi][ni], 0, 0, 0); \
    } while (0)

    // prologue: stage tile 0 fully (8 loads), one-time full drain
    STAGE_A(0, 0); STAGE_B(0, 0); STAGE_B(0, 1); STAGE_A(0, 1);
    asm volatile("s_waitcnt vmcnt(0)" ::: "memory");
    __builtin_amdgcn_s_barrier();
    SB0();

    #pragma unroll 1
    for (int t = 0; t < NT; ++t) {
        const size_t pf = (t + 1 < NT);

        // ---- phase 1: read A-u1 (mi0-3) + B-u1 (ni0-1) | MFMA Q00 ----
        #pragma unroll
        for (int mi = 0; mi < 4; ++mi) {
            af[mi][0] = *(const bf16x8*)(AsB + aBase + mi * 2048 + px0);
            af[mi][1] = *(const bf16x8*)(AsB + aBase + mi * 2048 + px1);
        }
        #pragma unroll
        for (int ni = 0; ni < 2; ++ni) {
            bf[ni][0] = *(const bf16x8*)(BsB + bBase + ni * 2048 + px0);
            bf[ni][1] = *(const bf16x8*)(BsB + bBase + ni * 2048 + px1);
        }
        SB0();
        __builtin_amdgcn_s_barrier();
        asm volatile("s_waitcnt lgkmcnt(0)" ::: "memory");
        SB0();
        __builtin_amdgcn_s_setprio(1);
        MFMA_Q(0, 0);
        __builtin_amdgcn_s_setprio(0);
        SB0();
        asm volatile("s_waitcnt vmcnt(2)" ::: "memory"); // Bu2(t) landed for ph2
        __builtin_amdgcn_s_barrier();
        SB0();

        // ---- phase 2: read B-u2 (ni2-3) | stage A-u1(t+1) | MFMA Q01 ----
        #pragma unroll
        for (int ni = 2; ni < 4; ++ni) {
            bf[ni][0] = *(const bf16x8*)(BsB + bBase + ni * 2048 + px0);
            bf[ni][1] = *(const bf16x8*)(BsB + bBase + ni * 2048 + px1);
        }
        if (pf) STAGE_A(t + 1, 0);
        SB0();
        __builtin_amdgcn_s_barrier();
        asm volatile("s_waitcnt lgkmcnt(0)" ::: "memory");
        SB0();
        __builtin_amdgcn_s_setprio(1);
        MFMA_Q(0, 1);
        __builtin_amdgcn_s_setprio(0);
        SB0();
        asm volatile("s_waitcnt vmcnt(2)" ::: "memory"); // Au2(t) landed for ph3
        __builtin_amdgcn_s_barrier();
        SB0();

        // ---- phase 3: read A-u2 (mi4-7) | stage B-u1,B-u2(t+1) | MFMA Q10 ----
        #pragma unroll
        for (int mi = 0; mi < 4; ++mi) {
            af[mi][0] = *(const bf16x8*)(AsB + aBase + 8192 + mi * 2048 + px0);
            af[mi][1] = *(const bf16x8*)(AsB + aBase + 8192 + mi * 2048 + px1);
        }
        if (pf) { STAGE_B(t + 1, 0); STAGE_B(t + 1, 1); }
        SB0();
        __builtin_amdgcn_s_barrier();
        asm volatile("s_waitcnt lgkmcnt(0)" ::: "memory");
        SB0();
        __builtin_amdgcn_s_setprio(1);
        MFMA_Q(1, 0);
        __builtin_amdgcn_s_setprio(0);
        SB0();
        __builtin_amdgcn_s_barrier();
        SB0();

        // ---- phase 4: stage A-u2(t+1) | MFMA Q11 | gate for ph1(t+1) ----
        if (pf) STAGE_A(t + 1, 1);
        SB0();
        __builtin_amdgcn_s_barrier();
        SB0();
        __builtin_amdgcn_s_setprio(1);
        MFMA_Q(1, 1);
        __builtin_amdgcn_s_setprio(0);
        SB0();
        asm volatile("s_waitcnt vmcnt(4)" ::: "memory"); // Au1',Bu1' landed
        __builtin_amdgcn_s_barrier();
        SB0();
    }
#undef MFMA_Q
#undef SB0
#undef STAGE_B
#undef STAGE_A

    // epilogue: D row = quad*4 + r, col = q16 (per 16x16 tile)
    #pragma unroll
    for (int mi = 0; mi < 8; ++mi) {
        #pragma unroll
        for (int ni = 0; ni < 4; ++ni) {
            const int col = col0 + wc * 64 + ni * 16 + q16;
            #pragma unroll
            for (int r = 0; r < 4; ++r) {
                const int row = row0 + wr * 128 + mi * 16 + quad * 4 + r;
                if (OUT_BF16)
                    ((__bf16*)Cv)[(size_t)row * N + col] = (__bf16)acc[mi][ni][r];
                else
                    ((float*)Cv)[(size_t)row * N + col] = acc[mi][ni][r];
            }
        }
    }
}

// ---------------- per-token head attention, MFMA, one wave per token ----------------
__global__ __launch_bounds__(256) void attn_mfma_kernel(const __bf16* __restrict__ qkv,
                                                        __bf16* __restrict__ ao) {
    const int tok  = blockIdx.x * 4 + (threadIdx.x >> 6);
    const int lane = threadIdx.x & 63;
    const int quad = lane >> 4;
    const int q16  = lane & 15;

    const __bf16* base = qkv + (size_t)tok * 3072;

    const bf16x8 qf0 = *(const bf16x8*)(base + lane * 8);
    const bf16x8 qf1 = *(const bf16x8*)(base + 512 + lane * 8);
    const bf16x8 kf0 = *(const bf16x8*)(base + 1024 + lane * 8);
    const bf16x8 kf1 = *(const bf16x8*)(base + 1536 + lane * 8);

    f32x4 st = {0.f, 0.f, 0.f, 0.f};
    st = __builtin_amdgcn_mfma_f32_16x16x32_bf16(kf0, qf0, st, 0, 0, 0);
    st = __builtin_amdgcn_mfma_f32_16x16x32_bf16(kf1, qf1, st, 0, 0, 0);

    float s0 = st[0] * 0.125f, s1 = st[1] * 0.125f, s2 = st[2] * 0.125f, s3 = st[3] * 0.125f;
    float m = fmaxf(fmaxf(s0, s1), fmaxf(s2, s3));
    m = fmaxf(m, __shfl_xor(m, 16));
    m = fmaxf(m, __shfl_xor(m, 32));
    float e0 = __expf(s0 - m), e1 = __expf(s1 - m), e2 = __expf(s2 - m), e3 = __expf(s3 - m);
    float sum = e0 + e1 + e2 + e3;
    sum += __shfl_xor(sum, 16);
    sum += __shfl_xor(sum, 32);
    const float inv = 1.f / sum;

    union { __bf16 h[2]; int i; } u01, u23;
    u01.h[0] = (__bf16)(e0 * inv); u01.h[1] = (__bf16)(e1 * inv);
    u23.h[0] = (__bf16)(e2 * inv); u23.h[1] = (__bf16)(e3 * inv);

    const int src0 = quad * 32 + q16;
    const int src1 = src0 + 16;
    union { int i[4]; bf16x8 v; } af;
    af.i[0] = __shfl(u01.i, src0);
    af.i[1] = __shfl(u23.i, src0);
    af.i[2] = __shfl(u01.i, src1);
    af.i[3] = __shfl(u23.i, src1);
    if (quad >= 2) { af.i[0] = 0; af.i[1] = 0; af.i[2] = 0; af.i[3] = 0; }

    const __bf16* vb = base + 2048;
    f32x4 accs[4];
    #pragma unroll
    for (int c = 0; c < 4; ++c) {
        bf16x8 bfv = {};
        if (quad < 2)
            bfv = *(const bf16x8*)(vb + (c * 16 + q16) * 16 + quad * 8);
        f32x4 z = {0.f, 0.f, 0.f, 0.f};
        accs[c] = __builtin_amdgcn_mfma_f32_16x16x32_bf16(af.v, bfv, z, 0, 0, 0);
    }

    union { __bf16 h[16]; bf16x8 v[2]; } o;
    #pragma unroll
    for (int c = 0; c < 4; ++c)
        #pragma unroll
        for (int r = 0; r < 4; ++r)
            o.h[c * 4 + r] = (__bf16)accs[c][r];
    __bf16* outp = ao + (size_t)tok * 1024 + lane * 16;
    *(bf16x8*)outp = o.v[0];
    *(bf16x8*)(outp + 8) = o.v[1];
}

// ---------------- launch ----------------
extern "C" void kernel_launch(void* const* d_in, const int* in_sizes, int n_in,
                              void* d_out, int out_size, void* d_ws, size_t ws_size,
                              hipStream_t stream) {
    const float* x    = (const float*)d_in[0]; // 16384 x 1024
    const float* Wqkv = (const float*)d_in[1]; // 1024 x 3072
    const float* Wout = (const float*)d_in[2]; // 1024 x 1024
    float* out = (float*)d_out;                // 16384 x 1024

    char* ws = (char*)d_ws;
    __bf16* xb    = (__bf16*)(ws);                                   // 32 MiB
    __bf16* wqkvT = (__bf16*)(ws + 33554432);                        // 6 MiB  (3072 x 1024, row-permuted)
    __bf16* woutT = (__bf16*)(ws + 33554432 + 6291456);              // 2 MiB  (1024 x 1024, k-permuted)
    __bf16* qkv   = (__bf16*)(ws + 33554432 + 6291456 + 2097152);    // 96 MiB (16384 x 3072, permuted)
    __bf16* ao    = (__bf16*)(ws + 33554432 + 6291456 + 2097152 + 100663296); // 32 MiB (permuted)

    // convert x (16M elems, 4/thread)
    cvt_bf16_kernel<<<16384, 256, 0, stream>>>((const float4*)x, (bf16x4*)xb, 4194304);
    // transpose+convert weights (with absorbed layout permutations)
    transpose_qkv_kernel<<<dim3(96, 32), dim3(32, 8), 0, stream>>>(Wqkv, wqkvT);
    transpose_wout_kernel<<<dim3(32, 32), dim3(32, 8), 0, stream>>>(Wout, woutT);
    // GEMM1: qkv = xb @ wqkvT^T (16384 x 3072), 256x256 tiles: 64 x 12 = 768 blocks
    gemm_bt<1><<<768, 512, 0, stream>>>(xb, wqkvT, (void*)qkv, 3072, 1024);
    // per-token attention (one wave per token, 4 waves/block, no LDS/barrier)
    attn_mfma_kernel<<<4096, 256, 0, stream>>>(qkv, ao);
    // GEMM2: out = ao @ woutT^T (fp32 out), 256x256 tiles: 64 x 4 = 256 blocks
    gemm_bt<0><<<256, 512, 0, stream>>>(ao, woutT, (void*)out, 1024, 1024);
}